// Round 2
// baseline (382.509 us; speedup 1.0000x reference)
//
#include <hip/hip_runtime.h>
#include <math.h>

// Problem constants (fixed by setup_inputs)
#define NB 2
#define NH 12
#define NW 12
#define NK 3
#define NI 32
#define NO 32
#define NA 16                 // a*a = 16 pose elements
#define NBHW (NB*NH*NW)       // 288 spatial positions
#define NC (NK*NK*NI)         // 288 children per position
#define CSTR (NO*NA)          // 512 floats per child (o-major, a-minor)
#define VPB (NC*CSTR)         // 147456 votes floats per bhw
#define HR 14
#define WR 14
#define EPSF 1e-7f
#define MINVAR 5e-4f
#define TEMP0 0.0005f         // 0.01*(1-0.95^1), m_step it=0
#define TEMPF 0.00142625f     // 0.01*(1-0.95^3), final m_step it=ITERATIONS=2

#define CH 8                  // chunks of the child dim for votes passes
#define CPC (NC/CH)           // 36 children per chunk
#define ITERS (CPC/2)         // 18 iterations, 2 children per block-iteration

// ---- Workspace layout (float offsets) ----
// Zeroed region (atomic accumulators):
#define A_S1 0                // [bhw][o][a] 147456
#define A_S2 147456           // 147456
#define A_SR 294912           // [bhw] 288
#define D_S1 295200           // 147456
#define D_S2 442656           // 147456
#define D_SR 590112           // [bhw][o] 9216
#define DENSE_OFF 599328      // [b][y'][x'][i] 12544
#define BM_OFF 611872         // per-block max, NBHW*CH = 2304
#define ZERO_N 614176
// Non-zeroed:
#define MU_OFF 614176         // [bhw][a*32+o] 147456
#define W_OFF  761632         // inv(2*sig) 147456
#define L_OFF  909088         // [bhw][o] 9216
#define M_OFF  918304         // global max scalar (+pad)
#define LOGNUM_OFF 918308     // [bhw][c][o] 2654208
#define DENSE_N (NB*HR*WR*NI)

// ---------------- Kernel A: m_step 1 partial moments (R uniform = 1/NO) ----
// grid = NBHW*CH, block = 256.
// t -> child_sub = t>>7, rem = t&127, o = rem>>2, quad = rem&3 (a = 4*quad+j)
// wave reads 1024B contiguous votes per iteration.
__global__ __launch_bounds__(256) void kA(const float* __restrict__ votes,
        const float* __restrict__ acts, float* __restrict__ ws) {
    __shared__ float s_acts[CPC];
    const int bid = blockIdx.x;
    const int bhw = bid >> 3;
    const int cbase = (bid & 7) * CPC;
    const int t = threadIdx.x;
    if (t < CPC) s_acts[t] = acts[bhw*NC + cbase + t] * (1.0f/NO);
    __syncthreads();
    const int child_sub = t >> 7;
    const int rem = t & 127;
    const int o = rem >> 2;
    const int quad = rem & 3;
    const float4* vb4 = (const float4*)votes + (size_t)bhw*(VPB/4);
    float s1[4] = {0,0,0,0}, s2[4] = {0,0,0,0};
    float sumR = 0.f;
    #pragma unroll 6
    for (int it = 0; it < ITERS; ++it) {
        const int c_loc = it*2 + child_sub;
        float4 v = vb4[(size_t)(cbase + c_loc)*128 + rem];
        float ra = s_acts[c_loc];
        s1[0] += ra*v.x; s2[0] = fmaf(ra*v.x, v.x, s2[0]);
        s1[1] += ra*v.y; s2[1] = fmaf(ra*v.y, v.y, s2[1]);
        s1[2] += ra*v.z; s2[2] = fmaf(ra*v.z, v.z, s2[2]);
        s1[3] += ra*v.w; s2[3] = fmaf(ra*v.w, v.w, s2[3]);
        sumR += ra;
    }
    const int base = bhw*512 + o*16 + quad*4;
    #pragma unroll
    for (int j = 0; j < 4; ++j) {
        atomicAdd(&ws[A_S1 + base + j], s1[j]);
        atomicAdd(&ws[A_S2 + base + j], s2[j]);
    }
    if (rem == 0) atomicAdd(&ws[A_SR + bhw], sumR);  // both child_subs add
}

// ---------------- Kernel A2: finalize mu/sig, cost, L ----------------
// grid = NBHW*2, block = 256, t = (o_loc<<4)|a
__global__ __launch_bounds__(256) void kA2(const float* __restrict__ beta_a,
        const float* __restrict__ beta_u, float* __restrict__ ws) {
    const int bid = blockIdx.x;
    const int bhw = bid >> 1;
    const int obase = (bid & 1) * 16;
    const int t = threadIdx.x;
    const int a = t & 15;
    const int o = obase + (t >> 4);
    const int idx = bhw*512 + o*16 + a;
    float s1 = ws[A_S1 + idx];
    float s2 = ws[A_S2 + idx];
    float sumR = ws[A_SR + bhw];
    float mu  = s1 / (sumR + EPSF);
    float sig = (s2 - mu*(2.f*s1 - mu*sumR)) / (sumR + EPSF) + MINVAR;
    ws[MU_OFF + bhw*512 + a*32 + o] = mu;
    ws[W_OFF  + bhw*512 + a*32 + o] = 0.5f / sig;
    float cost = (beta_u[o] - 0.5f*logf(sig + EPSF)) * sumR;
    float ps   = logf(6.2831853071795864f * sig);
    #pragma unroll
    for (int d = 1; d < 16; d <<= 1) {
        cost += __shfl_xor(cost, d);
        ps   += __shfl_xor(ps, d);
    }
    if (a == 0) {
        float aj = 1.0f/(1.0f + expf(-TEMP0*(beta_a[o] - cost)));
        ws[L_OFF + bhw*32 + o] = logf(aj) - ps;
    }
}

// ---------------- Kernel B: lognum + per-block max ----------------
// grid = NBHW*CH, block = 256. Same thread map as kA; cross-quad shuffle
// completes the a-sum; quad 0 writes lognum.
__global__ __launch_bounds__(256) void kB(const float* __restrict__ votes,
                                          float* __restrict__ ws) {
    const int bid = blockIdx.x;
    const int bhw = bid >> 3;
    const int cbase = (bid & 7) * CPC;
    const int t = threadIdx.x;
    const int child_sub = t >> 7;
    const int rem = t & 127;
    const int o = rem >> 2;
    const int quad = rem & 3;
    float mur[4], wr[4];
    #pragma unroll
    for (int j = 0; j < 4; ++j) {
        mur[j] = ws[MU_OFF + bhw*512 + (quad*4+j)*32 + o];
        wr[j]  = ws[W_OFF  + bhw*512 + (quad*4+j)*32 + o];
    }
    const float L = ws[L_OFF + bhw*32 + o];
    const float4* vb4 = (const float4*)votes + (size_t)bhw*(VPB/4);
    float* lp = ws + LOGNUM_OFF + (size_t)bhw*(NC*NO);
    float tmax = -3.0e38f;
    #pragma unroll 6
    for (int it = 0; it < ITERS; ++it) {
        const int c = cbase + it*2 + child_sub;
        float4 v = vb4[(size_t)c*128 + rem];
        float d0 = v.x - mur[0];
        float acc = d0*d0*wr[0];
        float d1 = v.y - mur[1]; acc = fmaf(d1*d1, wr[1], acc);
        float d2 = v.z - mur[2]; acc = fmaf(d2*d2, wr[2], acc);
        float d3 = v.w - mur[3]; acc = fmaf(d3*d3, wr[3], acc);
        acc += __shfl_xor(acc, 1);
        acc += __shfl_xor(acc, 2);         // all quads now hold the full a-sum
        float ln = L - acc;
        if (quad == 0) lp[c*32 + o] = ln;
        tmax = fmaxf(tmax, ln);
    }
    #pragma unroll
    for (int d = 1; d < 64; d <<= 1) tmax = fmaxf(tmax, __shfl_xor(tmax, d));
    __shared__ float smax[4];
    if ((t & 63) == 0) smax[t >> 6] = tmax;
    __syncthreads();
    if (t == 0)
        ws[BM_OFF + bid] = fmaxf(fmaxf(smax[0], smax[1]), fmaxf(smax[2], smax[3]));
}

// ---------------- Kernel Bmax: reduce block maxes -> scalar ----------------
__global__ __launch_bounds__(256) void kBmax(float* __restrict__ ws) {
    const int t = threadIdx.x;
    float m = -3.0e38f;
    for (int i = t; i < NBHW*CH; i += 256) m = fmaxf(m, ws[BM_OFF + i]);
    #pragma unroll
    for (int d = 1; d < 64; d <<= 1) m = fmaxf(m, __shfl_xor(m, d));
    __shared__ float sm[4];
    if ((t & 63) == 0) sm[t >> 6] = m;
    __syncthreads();
    if (t == 0) ws[M_OFF] = fmaxf(fmaxf(sm[0], sm[1]), fmaxf(sm[2], sm[3]));
}

// ---------------- Kernel C: sum_o exp(lognum-M), scatter to dense ----------
// grid = NBHW*4, block = 256; t -> (c_loc = t>>5, o = t&31)
__global__ __launch_bounds__(256) void kC(float* __restrict__ ws) {
    const int bid = blockIdx.x;
    const int bhw = bid >> 2;
    const int cbase = (bid & 3) * 72;
    const int t = threadIdx.x;
    const int b = bhw / (NH*NW);
    const int rem = bhw % (NH*NW);
    const int y = rem / NW, x = rem % NW;
    const float M = ws[M_OFF];
    const float* lp = ws + LOGNUM_OFF + (size_t)bhw*(NC*NO);
    float* dense = ws + DENSE_OFF;
    const int o = t & 31;
    for (int it = 0; it < 9; ++it) {
        const int c = cbase + it*8 + (t >> 5);
        float s = expf(lp[c*32 + o] - M);
        #pragma unroll
        for (int d = 1; d < 32; d <<= 1) s += __shfl_xor(s, d);
        if (o == 0) {
            const int i = c & 31, kk = c >> 5;
            const int ky = kk / 3, kx = kk % 3;
            atomicAdd(&dense[((b*HR + y+ky)*WR + (x+kx))*NI + i], s);
        }
    }
}

// ---------------- Kernel D: final m_step partial moments ----------------
// grid = NBHW*CH, block = 256. ra = acts/(denom+eps)*exp(lognum-M) staged in LDS.
__global__ __launch_bounds__(256) void kD(const float* __restrict__ votes,
        const float* __restrict__ acts, float* __restrict__ ws) {
    __shared__ float s_rd[CPC];
    __shared__ float s_ra[CPC*NO];
    const int bid = blockIdx.x;
    const int bhw = bid >> 3;
    const int cbase = (bid & 7) * CPC;
    const int t = threadIdx.x;
    const int b = bhw / (NH*NW);
    const int remhw = bhw % (NH*NW);
    const int y = remhw / NW, x = remhw % NW;
    if (t < CPC) {
        const int c = cbase + t;
        const int i = c & 31, kk = c >> 5;
        const int ky = kk / 3, kx = kk % 3;
        float dn = ws[DENSE_OFF + ((b*HR + y+ky)*WR + (x+kx))*NI + i];
        s_rd[t] = acts[bhw*NC + c] / (dn + EPSF);
    }
    __syncthreads();
    const float M = ws[M_OFF];
    const float* lp = ws + LOGNUM_OFF + (size_t)bhw*(NC*NO) + (size_t)cbase*32;
    for (int idx = t; idx < CPC*NO; idx += 256) {
        s_ra[idx] = s_rd[idx >> 5] * expf(lp[idx] - M);
    }
    __syncthreads();
    const int child_sub = t >> 7;
    const int rem = t & 127;
    const int o = rem >> 2;
    const int quad = rem & 3;
    const float4* vb4 = (const float4*)votes + (size_t)bhw*(VPB/4);
    float s1[4] = {0,0,0,0}, s2[4] = {0,0,0,0};
    float sumR = 0.f;
    #pragma unroll 6
    for (int it = 0; it < ITERS; ++it) {
        const int c_loc = it*2 + child_sub;
        float4 v = vb4[(size_t)(cbase + c_loc)*128 + rem];
        float ra = s_ra[c_loc*32 + o];           // 4-lane broadcast, conflict-free
        s1[0] += ra*v.x; s2[0] = fmaf(ra*v.x, v.x, s2[0]);
        s1[1] += ra*v.y; s2[1] = fmaf(ra*v.y, v.y, s2[1]);
        s1[2] += ra*v.z; s2[2] = fmaf(ra*v.z, v.z, s2[2]);
        s1[3] += ra*v.w; s2[3] = fmaf(ra*v.w, v.w, s2[3]);
        sumR += ra;
    }
    const int base = bhw*512 + o*16 + quad*4;
    #pragma unroll
    for (int j = 0; j < 4; ++j) {
        atomicAdd(&ws[D_S1 + base + j], s1[j]);
        atomicAdd(&ws[D_S2 + base + j], s2[j]);
    }
    if (quad == 0) atomicAdd(&ws[D_SR + bhw*32 + o], sumR);
}

// ---------------- Kernel D2: finalize outputs ----------------
// grid = NBHW*2, block = 256, t = (o_loc<<4)|a
__global__ __launch_bounds__(256) void kD2(const float* __restrict__ beta_a,
        const float* __restrict__ beta_u, const float* __restrict__ ws,
        float* __restrict__ out) {
    const int bid = blockIdx.x;
    const int bhw = bid >> 1;
    const int obase = (bid & 1) * 16;
    const int t = threadIdx.x;
    const int a = t & 15;
    const int o = obase + (t >> 4);
    const int idx = bhw*512 + o*16 + a;
    float s1 = ws[D_S1 + idx];
    float s2 = ws[D_S2 + idx];
    float sumR = ws[D_SR + bhw*32 + o];
    float mu  = s1 / (sumR + EPSF);
    float sig = (s2 - mu*(2.f*s1 - mu*sumR)) / (sumR + EPSF) + MINVAR;
    out[bhw*512 + obase*16 + t] = mu;            // poses (b,h,w,o,a,a)
    float cost = (beta_u[o] - 0.5f*logf(sig + EPSF)) * sumR;
    #pragma unroll
    for (int d = 1; d < 16; d <<= 1) cost += __shfl_xor(cost, d);
    if (a == 0) {
        float aj = 1.0f/(1.0f + expf(-TEMPF*(beta_a[o] - cost)));
        out[NBHW*512 + bhw*32 + o] = aj;         // acts (b,h,w,o)
    }
}

extern "C" void kernel_launch(void* const* d_in, const int* in_sizes, int n_in,
                              void* d_out, int out_size, void* d_ws, size_t ws_size,
                              hipStream_t stream) {
    const float* votes  = (const float*)d_in[0];
    const float* acts   = (const float*)d_in[1];
    const float* beta_a = (const float*)d_in[2];
    const float* beta_u = (const float*)d_in[3];
    float* ws  = (float*)d_ws;
    float* out = (float*)d_out;

    hipMemsetAsync(ws, 0, ZERO_N*sizeof(float), stream);
    kA   <<<NBHW*CH, 256, 0, stream>>>(votes, acts, ws);
    kA2  <<<NBHW*2,  256, 0, stream>>>(beta_a, beta_u, ws);
    kB   <<<NBHW*CH, 256, 0, stream>>>(votes, ws);
    kBmax<<<1,       256, 0, stream>>>(ws);
    kC   <<<NBHW*4,  256, 0, stream>>>(ws);
    kD   <<<NBHW*CH, 256, 0, stream>>>(votes, acts, ws);
    kD2  <<<NBHW*2,  256, 0, stream>>>(beta_a, beta_u, ws, out);
}

// Round 5
// 317.282 us; speedup vs baseline: 1.2056x; 1.2056x over previous
//
#include <hip/hip_runtime.h>
#include <math.h>

// Problem constants (fixed by setup_inputs)
#define NB 2
#define NH 12
#define NW 12
#define NK 3
#define NI 32
#define NO 32
#define NA 16                 // a*a = 16 pose elements
#define NBHW (NB*NH*NW)       // 288 spatial positions
#define NC (NK*NK*NI)         // 288 children per position
#define CSTR (NO*NA)          // 512 floats per child (o-major, a-minor)
#define VPB (NC*CSTR)         // 147456 votes floats per bhw
#define HR 14
#define WR 14
#define EPSF 1e-7f
#define MINVAR 5e-4f
#define TEMP0 0.0005f         // 0.01*(1-0.95^1), m_step it=0
#define TEMPF 0.00142625f     // 0.01*(1-0.95^3), final m_step it=ITERATIONS=2

#define CH 8                  // chunks of the child dim for votes passes
#define CPC (NC/CH)           // 36 children per chunk
#define ITERS (CPC/2)         // 18 iterations, 2 children per block-iteration
#define NBLK (NBHW*CH)        // 2304 chunk-blocks

// ---- Workspace layout (float offsets) ----
// Chunk-private partial slots (plain coalesced stores, no atomics):
#define PA_S1 0                        // [bid][512] (o*16+a)
#define PA_S2 (PA_S1 + NBLK*512)
#define PA_SR (PA_S2 + NBLK*512)       // [bid]
#define PD_S1 (PA_SR + NBLK)
#define PD_S2 (PD_S1 + NBLK*512)
#define PD_SR (PD_S2 + NBLK*512)       // [bid][32] (per-o)
// Round-2-style intermediates:
#define MU_OFF (PD_SR + NBLK*32)       // [bhw][a*32+o] 147456
#define W_OFF  (MU_OFF + NBHW*512)     // inv(2*sig) 147456
#define L_OFF  (W_OFF + NBHW*512)      // [bhw][o] 9216
#define BM_OFF (L_OFF + NBHW*32)       // [bid] per-block lognum max
#define M_OFF  (BM_OFF + NBLK)         // global max scalar
#define DENSE_OFF (M_OFF + 16)         // [b][y'][x'][i]
#define DENSE_N (NB*HR*WR*NI)          // 12544
#define LOGNUM_OFF (DENSE_OFF + DENSE_N)  // [bhw][c][o]

// ---------------- Kernel A: m_step 1 partial moments (R uniform = 1/NO) ----
// grid = NBLK, block = 256.
// t -> child_sub = t>>7, rem = t&127, o = rem>>2, quad = rem&3 (a = 4*quad+j)
// wave reads 1024B contiguous votes per iteration.
__global__ __launch_bounds__(256) void kA(const float* __restrict__ votes,
        const float* __restrict__ acts, float* __restrict__ ws) {
    __shared__ float s_acts[CPC];
    __shared__ float4 r1[128], r2[128];
    __shared__ float sR1;
    const int bid = blockIdx.x;
    const int bhw = bid >> 3;
    const int cbase = (bid & 7) * CPC;
    const int t = threadIdx.x;
    if (t < CPC) s_acts[t] = acts[bhw*NC + cbase + t] * (1.0f/NO);
    __syncthreads();
    const int child_sub = t >> 7;
    const int rem = t & 127;
    const float4* vb4 = (const float4*)votes + (size_t)bhw*(VPB/4);
    float s1[4] = {0,0,0,0}, s2[4] = {0,0,0,0};
    float sumR = 0.f;
    #pragma unroll 6
    for (int it = 0; it < ITERS; ++it) {
        const int c_loc = it*2 + child_sub;
        float4 v = vb4[(size_t)(cbase + c_loc)*128 + rem];
        float ra = s_acts[c_loc];
        s1[0] += ra*v.x; s2[0] = fmaf(ra*v.x, v.x, s2[0]);
        s1[1] += ra*v.y; s2[1] = fmaf(ra*v.y, v.y, s2[1]);
        s1[2] += ra*v.z; s2[2] = fmaf(ra*v.z, v.z, s2[2]);
        s1[3] += ra*v.w; s2[3] = fmaf(ra*v.w, v.w, s2[3]);
        sumR += ra;
    }
    if (child_sub) {
        r1[rem] = make_float4(s1[0], s1[1], s1[2], s1[3]);
        r2[rem] = make_float4(s2[0], s2[1], s2[2], s2[3]);
        if (rem == 0) sR1 = sumR;
    }
    __syncthreads();
    if (!child_sub) {
        float4 o1 = r1[rem], o2 = r2[rem];
        ((float4*)(ws + PA_S1))[bid*128 + rem] =
            make_float4(s1[0]+o1.x, s1[1]+o1.y, s1[2]+o1.z, s1[3]+o1.w);
        ((float4*)(ws + PA_S2))[bid*128 + rem] =
            make_float4(s2[0]+o2.x, s2[1]+o2.y, s2[2]+o2.z, s2[3]+o2.w);
        if (rem == 0) ws[PA_SR + bid] = sumR + sR1;
    }
}

// ---------------- Kernel A2: reduce chunk slots; finalize mu/sig, cost, L --
// grid = NBHW*2, block = 256, t = (o_loc<<4)|a
__global__ __launch_bounds__(256) void kA2(const float* __restrict__ beta_a,
        const float* __restrict__ beta_u, float* __restrict__ ws) {
    const int bid = blockIdx.x;
    const int bhw = bid >> 1;
    const int obase = (bid & 1) * 16;
    const int t = threadIdx.x;
    const int a = t & 15;
    const int o = obase + (t >> 4);
    const int idx = o*16 + a;          // = obase*16 + t
    float s1 = 0.f, s2 = 0.f, sumR = 0.f;
    #pragma unroll
    for (int ch = 0; ch < 8; ++ch) {
        s1   += ws[PA_S1 + (size_t)(bhw*8 + ch)*512 + idx];
        s2   += ws[PA_S2 + (size_t)(bhw*8 + ch)*512 + idx];
        sumR += ws[PA_SR + bhw*8 + ch];
    }
    float mu  = s1 / (sumR + EPSF);
    float sig = (s2 - mu*(2.f*s1 - mu*sumR)) / (sumR + EPSF) + MINVAR;
    ws[MU_OFF + bhw*512 + a*32 + o] = mu;
    ws[W_OFF  + bhw*512 + a*32 + o] = 0.5f / sig;
    float cost = (beta_u[o] - 0.5f*logf(sig + EPSF)) * sumR;
    float ps   = logf(6.2831853071795864f * sig);
    #pragma unroll
    for (int d = 1; d < 16; d <<= 1) {
        cost += __shfl_xor(cost, d);
        ps   += __shfl_xor(ps, d);
    }
    if (a == 0) {
        float aj = 1.0f/(1.0f + expf(-TEMP0*(beta_a[o] - cost)));
        ws[L_OFF + bhw*32 + o] = logf(aj) - ps;
    }
}

// ---------------- Kernel B: lognum + per-block max (verbatim round 2) ------
// grid = NBLK, block = 256. Cross-quad shuffle completes the a-sum.
__global__ __launch_bounds__(256) void kB(const float* __restrict__ votes,
                                          float* __restrict__ ws) {
    const int bid = blockIdx.x;
    const int bhw = bid >> 3;
    const int cbase = (bid & 7) * CPC;
    const int t = threadIdx.x;
    const int child_sub = t >> 7;
    const int rem = t & 127;
    const int o = rem >> 2;
    const int quad = rem & 3;
    float mur[4], wr[4];
    #pragma unroll
    for (int j = 0; j < 4; ++j) {
        mur[j] = ws[MU_OFF + bhw*512 + (quad*4+j)*32 + o];
        wr[j]  = ws[W_OFF  + bhw*512 + (quad*4+j)*32 + o];
    }
    const float L = ws[L_OFF + bhw*32 + o];
    const float4* vb4 = (const float4*)votes + (size_t)bhw*(VPB/4);
    float* lp = ws + LOGNUM_OFF + (size_t)bhw*(NC*NO);
    float tmax = -3.0e38f;
    #pragma unroll 6
    for (int it = 0; it < ITERS; ++it) {
        const int c = cbase + it*2 + child_sub;
        float4 v = vb4[(size_t)c*128 + rem];
        float d0 = v.x - mur[0];
        float acc = d0*d0*wr[0];
        float d1 = v.y - mur[1]; acc = fmaf(d1*d1, wr[1], acc);
        float d2 = v.z - mur[2]; acc = fmaf(d2*d2, wr[2], acc);
        float d3 = v.w - mur[3]; acc = fmaf(d3*d3, wr[3], acc);
        acc += __shfl_xor(acc, 1);
        acc += __shfl_xor(acc, 2);         // all quads now hold the full a-sum
        float ln = L - acc;
        if (quad == 0) lp[c*32 + o] = ln;
        tmax = fmaxf(tmax, ln);
    }
    #pragma unroll
    for (int d = 1; d < 64; d <<= 1) tmax = fmaxf(tmax, __shfl_xor(tmax, d));
    __shared__ float smax[4];
    if ((t & 63) == 0) smax[t >> 6] = tmax;
    __syncthreads();
    if (t == 0)
        ws[BM_OFF + bid] = fmaxf(fmaxf(smax[0], smax[1]), fmaxf(smax[2], smax[3]));
}

// ---------------- Kernel Bmax: reduce block maxes -> scalar ----------------
__global__ __launch_bounds__(256) void kBmax(float* __restrict__ ws) {
    const int t = threadIdx.x;
    float m = -3.0e38f;
    for (int i = t; i < NBLK; i += 256) m = fmaxf(m, ws[BM_OFF + i]);
    #pragma unroll
    for (int d = 1; d < 64; d <<= 1) m = fmaxf(m, __shfl_xor(m, d));
    __shared__ float sm[4];
    if ((t & 63) == 0) sm[t >> 6] = m;
    __syncthreads();
    if (t == 0) ws[M_OFF] = fmaxf(fmaxf(sm[0], sm[1]), fmaxf(sm[2], sm[3]));
}

// ---------------- Kernel C: sum_o ap, scatter to dense ---------------------
// grid = NBHW*4, block = 256; t -> (c_loc = t>>5, o = t&31)
__global__ __launch_bounds__(256) void kC(float* __restrict__ ws) {
    const int bid = blockIdx.x;
    const int bhw = bid >> 2;
    const int cbase = (bid & 3) * 72;
    const int t = threadIdx.x;
    const int b = bhw / (NH*NW);
    const int rem = bhw % (NH*NW);
    const int y = rem / NW, x = rem % NW;
    const float M = ws[M_OFF];
    const float* lp = ws + LOGNUM_OFF + (size_t)bhw*(NC*NO);
    float* dense = ws + DENSE_OFF;
    const int o = t & 31;
    for (int it = 0; it < 9; ++it) {
        const int c = cbase + it*8 + (t >> 5);
        float s = expf(lp[c*32 + o] - M);
        #pragma unroll
        for (int d = 1; d < 32; d <<= 1) s += __shfl_xor(s, d);
        if (o == 0) {
            const int i = c & 31, kk = c >> 5;
            const int ky = kk / 3, kx = kk % 3;
            atomicAdd(&dense[((b*HR + y+ky)*WR + (x+kx))*NI + i], s);
        }
    }
}

// ---------------- Kernel D: final m_step partial moments -------------------
// grid = NBLK, block = 256. Slot tail, NO quad-shuffle on sumR (the r3/r4 bug:
// all 4 quads hold identical sumR, so reducing over quads quadrupled it).
__global__ __launch_bounds__(256) void kD(const float* __restrict__ votes,
        const float* __restrict__ acts, float* __restrict__ ws) {
    __shared__ float s_rd[CPC];
    __shared__ float s_ra[CPC*NO];
    __shared__ float4 r1[128], r2[128];
    __shared__ float sSR[64];
    const int bid = blockIdx.x;
    const int bhw = bid >> 3;
    const int cbase = (bid & 7) * CPC;
    const int t = threadIdx.x;
    const int b = bhw / (NH*NW);
    const int remhw = bhw % (NH*NW);
    const int y = remhw / NW, x = remhw % NW;
    if (t < CPC) {
        const int c = cbase + t;
        const int i = c & 31, kk = c >> 5;
        const int ky = kk / 3, kx = kk % 3;
        float dn = ws[DENSE_OFF + ((b*HR + y+ky)*WR + (x+kx))*NI + i];
        s_rd[t] = acts[bhw*NC + c] / (dn + EPSF);
    }
    __syncthreads();
    const float M = ws[M_OFF];
    const float* lp = ws + LOGNUM_OFF + (size_t)bhw*(NC*NO) + (size_t)cbase*32;
    for (int idx = t; idx < CPC*NO; idx += 256)
        s_ra[idx] = s_rd[idx >> 5] * expf(lp[idx] - M);
    __syncthreads();
    const int child_sub = t >> 7;
    const int rem = t & 127;
    const int o = rem >> 2;
    const int quad = rem & 3;
    const float4* vb4 = (const float4*)votes + (size_t)bhw*(VPB/4);
    float s1[4] = {0,0,0,0}, s2[4] = {0,0,0,0};
    float sumR = 0.f;
    #pragma unroll 6
    for (int it = 0; it < ITERS; ++it) {
        const int c_loc = it*2 + child_sub;
        float4 v = vb4[(size_t)(cbase + c_loc)*128 + rem];
        float ra = s_ra[c_loc*32 + o];          // 4-lane broadcast
        s1[0] += ra*v.x; s2[0] = fmaf(ra*v.x, v.x, s2[0]);
        s1[1] += ra*v.y; s2[1] = fmaf(ra*v.y, v.y, s2[1]);
        s1[2] += ra*v.z; s2[2] = fmaf(ra*v.z, v.z, s2[2]);
        s1[3] += ra*v.w; s2[3] = fmaf(ra*v.w, v.w, s2[3]);
        sumR += ra;
    }
    // per-(child_sub, o) partial: quads are identical, take quad 0's only
    if (quad == 0) sSR[child_sub*32 + o] = sumR;
    if (child_sub) {
        r1[rem] = make_float4(s1[0], s1[1], s1[2], s1[3]);
        r2[rem] = make_float4(s2[0], s2[1], s2[2], s2[3]);
    }
    __syncthreads();
    if (!child_sub) {
        float4 o1 = r1[rem], o2 = r2[rem];
        ((float4*)(ws + PD_S1))[bid*128 + rem] =
            make_float4(s1[0]+o1.x, s1[1]+o1.y, s1[2]+o1.z, s1[3]+o1.w);
        ((float4*)(ws + PD_S2))[bid*128 + rem] =
            make_float4(s2[0]+o2.x, s2[1]+o2.y, s2[2]+o2.z, s2[3]+o2.w);
    }
    if (t < 32) ws[PD_SR + bid*32 + t] = sSR[t] + sSR[32 + t];
}

// ---------------- Kernel D2: reduce chunk slots, write outputs -------------
// grid = NBHW*2, block = 256, t = (o_loc<<4)|a
__global__ __launch_bounds__(256) void kD2(const float* __restrict__ beta_a,
        const float* __restrict__ beta_u, const float* __restrict__ ws,
        float* __restrict__ out) {
    const int bid = blockIdx.x;
    const int bhw = bid >> 1;
    const int obase = (bid & 1) * 16;
    const int t = threadIdx.x;
    const int a = t & 15;
    const int o = obase + (t >> 4);
    float s1 = 0.f, s2 = 0.f, sumR = 0.f;
    #pragma unroll
    for (int ch = 0; ch < 8; ++ch) {
        s1   += ws[PD_S1 + (size_t)(bhw*8 + ch)*512 + obase*16 + t];
        s2   += ws[PD_S2 + (size_t)(bhw*8 + ch)*512 + obase*16 + t];
        sumR += ws[PD_SR + (bhw*8 + ch)*32 + o];
    }
    float mu  = s1 / (sumR + EPSF);
    float sig = (s2 - mu*(2.f*s1 - mu*sumR)) / (sumR + EPSF) + MINVAR;
    out[bhw*512 + obase*16 + t] = mu;            // poses (b,h,w,o,a,a)
    float cost = (beta_u[o] - 0.5f*logf(sig + EPSF)) * sumR;
    #pragma unroll
    for (int d = 1; d < 16; d <<= 1) cost += __shfl_xor(cost, d);
    if (a == 0) {
        float aj = 1.0f/(1.0f + expf(-TEMPF*(beta_a[o] - cost)));
        out[NBHW*512 + bhw*32 + o] = aj;         // acts (b,h,w,o)
    }
}

extern "C" void kernel_launch(void* const* d_in, const int* in_sizes, int n_in,
                              void* d_out, int out_size, void* d_ws, size_t ws_size,
                              hipStream_t stream) {
    const float* votes  = (const float*)d_in[0];
    const float* acts   = (const float*)d_in[1];
    const float* beta_a = (const float*)d_in[2];
    const float* beta_u = (const float*)d_in[3];
    float* ws  = (float*)d_ws;
    float* out = (float*)d_out;

    hipMemsetAsync(ws + DENSE_OFF, 0, DENSE_N*sizeof(float), stream);
    kA   <<<NBLK,   256, 0, stream>>>(votes, acts, ws);
    kA2  <<<NBHW*2, 256, 0, stream>>>(beta_a, beta_u, ws);
    kB   <<<NBLK,   256, 0, stream>>>(votes, ws);
    kBmax<<<1,      256, 0, stream>>>(ws);
    kC   <<<NBHW*4, 256, 0, stream>>>(ws);
    kD   <<<NBLK,   256, 0, stream>>>(votes, acts, ws);
    kD2  <<<NBHW*2, 256, 0, stream>>>(beta_a, beta_u, ws, out);
}

// Round 6
// 308.741 us; speedup vs baseline: 1.2389x; 1.0277x over previous
//
#include <hip/hip_runtime.h>
#include <math.h>

// Problem constants (fixed by setup_inputs)
#define NB 2
#define NH 12
#define NW 12
#define NK 3
#define NI 32
#define NO 32
#define NA 16                 // a*a = 16 pose elements
#define NBHW (NB*NH*NW)       // 288 spatial positions
#define NC (NK*NK*NI)         // 288 children per position
#define CSTR (NO*NA)          // 512 floats per child (o-major, a-minor)
#define VPB (NC*CSTR)         // 147456 votes floats per bhw
#define HR 14
#define WR 14
#define EPSF 1e-7f
#define MINVAR 5e-4f
#define TEMP0 0.0005f         // 0.01*(1-0.95^1), m_step it=0
#define TEMPF 0.00142625f     // 0.01*(1-0.95^3), final m_step it=ITERATIONS=2

#define CH 4                  // chunks of the child dim for votes passes
#define CPC (NC/CH)           // 72 children per chunk
#define ITERS (CPC/2)         // 36 iterations, 2 children per block-iteration
#define NBLK (NBHW*CH)        // 1152 chunk-blocks

// ---- Workspace layout (float offsets) ----
#define PA_S1 0                        // [bid][512] (o*16+a)
#define PA_S2 (PA_S1 + NBLK*512)
#define PA_SR (PA_S2 + NBLK*512)       // [bid]
#define PD_S1 (PA_SR + NBLK)
#define PD_S2 (PD_S1 + NBLK*512)
#define PD_SR (PD_S2 + NBLK*512)       // [bid][32] (per-o)
#define BM_OFF (PD_SR + NBLK*32)       // [bid] per-block lognum max
#define DENSE_OFF (BM_OFF + NBLK)      // [b][y'][x'][i]
#define DENSE_N (NB*HR*WR*NI)          // 12544
#define LOGNUM_OFF (DENSE_OFF + DENSE_N)  // [bhw][c][o]

// ---------------- Kernel A: m_step 1 partial moments (R uniform = 1/NO) ----
// grid = NBLK, block = 256. Also zeroes the dense grid (consumed by kC).
// t -> child_sub = t>>7, rem = t&127; wave reads 1024B contiguous votes/iter.
__global__ __launch_bounds__(256) void kA(const float* __restrict__ votes,
        const float* __restrict__ acts, float* __restrict__ ws) {
    __shared__ float s_acts[CPC];
    __shared__ float4 r1[128], r2[128];
    __shared__ float sR1;
    const int bid = blockIdx.x;
    const int bhw = bid >> 2;
    const int cbase = (bid & 3) * CPC;
    const int t = threadIdx.x;
    {   // fold dense-grid zeroing into the first kernel
        const int idx = bid*256 + t;
        if (idx < DENSE_N) ws[DENSE_OFF + idx] = 0.f;
    }
    if (t < CPC) s_acts[t] = acts[bhw*NC + cbase + t] * (1.0f/NO);
    __syncthreads();
    const int child_sub = t >> 7;
    const int rem = t & 127;
    const float4* vb4 = (const float4*)votes + (size_t)bhw*(VPB/4);
    float s1[4] = {0,0,0,0}, s2[4] = {0,0,0,0};
    float sumR = 0.f;
    #pragma unroll 6
    for (int it = 0; it < ITERS; ++it) {
        const int c_loc = it*2 + child_sub;
        float4 v = vb4[(size_t)(cbase + c_loc)*128 + rem];
        float ra = s_acts[c_loc];
        s1[0] += ra*v.x; s2[0] = fmaf(ra*v.x, v.x, s2[0]);
        s1[1] += ra*v.y; s2[1] = fmaf(ra*v.y, v.y, s2[1]);
        s1[2] += ra*v.z; s2[2] = fmaf(ra*v.z, v.z, s2[2]);
        s1[3] += ra*v.w; s2[3] = fmaf(ra*v.w, v.w, s2[3]);
        sumR += ra;
    }
    if (child_sub) {
        r1[rem] = make_float4(s1[0], s1[1], s1[2], s1[3]);
        r2[rem] = make_float4(s2[0], s2[1], s2[2], s2[3]);
        if (rem == 0) sR1 = sumR;
    }
    __syncthreads();
    if (!child_sub) {
        float4 o1 = r1[rem], o2 = r2[rem];
        ((float4*)(ws + PA_S1))[bid*128 + rem] =
            make_float4(s1[0]+o1.x, s1[1]+o1.y, s1[2]+o1.z, s1[3]+o1.w);
        ((float4*)(ws + PA_S2))[bid*128 + rem] =
            make_float4(s2[0]+o2.x, s2[1]+o2.y, s2[2]+o2.z, s2[3]+o2.w);
        if (rem == 0) ws[PA_SR + bid] = sumR + sR1;
    }
}

// ---------------- Kernel B: fused finalize (mu/sig/L in LDS) + lognum ------
// grid = NBLK, block = 256. Each block redundantly reduces its bhw's CH chunk
// slots (L2-hot), then runs the lognum pass over its own chunk.
__global__ __launch_bounds__(256) void kB(const float* __restrict__ votes,
        const float* __restrict__ beta_a, const float* __restrict__ beta_u,
        float* __restrict__ ws) {
    __shared__ float s_mu[512], s_w[512], s_L[32], smax[4];
    const int bid = blockIdx.x;
    const int bhw = bid >> 2;
    const int cbase = (bid & 3) * CPC;
    const int t = threadIdx.x;
    float sumR = 0.f;
    #pragma unroll
    for (int ch = 0; ch < CH; ++ch) sumR += ws[PA_SR + bhw*CH + ch];
    #pragma unroll
    for (int half = 0; half < 2; ++half) {
        const int idx = t + half*256;       // = o*16 + a
        float s1 = 0.f, s2 = 0.f;
        #pragma unroll
        for (int ch = 0; ch < CH; ++ch) {
            s1 += ws[PA_S1 + (size_t)(bhw*CH + ch)*512 + idx];
            s2 += ws[PA_S2 + (size_t)(bhw*CH + ch)*512 + idx];
        }
        const int o = idx >> 4, a = idx & 15;
        float mu  = s1 / (sumR + EPSF);
        float sig = (s2 - mu*(2.f*s1 - mu*sumR)) / (sumR + EPSF) + MINVAR;
        s_mu[a*32 + o] = mu;
        s_w [a*32 + o] = 0.5f / sig;
        float cost = (beta_u[o] - 0.5f*logf(sig + EPSF)) * sumR;
        float ps   = logf(6.2831853071795864f * sig);
        #pragma unroll
        for (int d = 1; d < 16; d <<= 1) {
            cost += __shfl_xor(cost, d);
            ps   += __shfl_xor(ps, d);
        }
        if (a == 0) {
            float aj = 1.0f/(1.0f + expf(-TEMP0*(beta_a[o] - cost)));
            s_L[o] = logf(aj) - ps;
        }
    }
    __syncthreads();
    const int child_sub = t >> 7;
    const int rem = t & 127;
    const int o = rem >> 2;
    const int quad = rem & 3;
    float mur[4], wr[4];
    #pragma unroll
    for (int j = 0; j < 4; ++j) {
        mur[j] = s_mu[(quad*4 + j)*32 + o];
        wr[j]  = s_w [(quad*4 + j)*32 + o];
    }
    const float L = s_L[o];
    const float4* vb4 = (const float4*)votes + (size_t)bhw*(VPB/4);
    float* lp = ws + LOGNUM_OFF + (size_t)bhw*(NC*NO);
    float tmax = -3.0e38f;
    #pragma unroll 6
    for (int it = 0; it < ITERS; ++it) {
        const int c = cbase + it*2 + child_sub;
        float4 v = vb4[(size_t)c*128 + rem];
        float d0 = v.x - mur[0];
        float acc = d0*d0*wr[0];
        float d1 = v.y - mur[1]; acc = fmaf(d1*d1, wr[1], acc);
        float d2 = v.z - mur[2]; acc = fmaf(d2*d2, wr[2], acc);
        float d3 = v.w - mur[3]; acc = fmaf(d3*d3, wr[3], acc);
        acc += __shfl_xor(acc, 1);
        acc += __shfl_xor(acc, 2);          // all quads hold the full a-sum
        float ln = L - acc;
        if (quad == 0) lp[c*32 + o] = ln;
        tmax = fmaxf(tmax, ln);
    }
    #pragma unroll
    for (int d = 1; d < 64; d <<= 1) tmax = fmaxf(tmax, __shfl_xor(tmax, d));
    if ((t & 63) == 0) smax[t >> 6] = tmax;
    __syncthreads();
    if (t == 0)
        ws[BM_OFF + bid] = fmaxf(fmaxf(smax[0], smax[1]), fmaxf(smax[2], smax[3]));
}

// ---------------- Kernel C: inline global max + sum_o ap, scatter ----------
// grid = NBHW*4, block = 256; t -> (c_loc = t>>5, o = t&31)
__global__ __launch_bounds__(256) void kC(float* __restrict__ ws) {
    __shared__ float smax[4];
    const int bid = blockIdx.x;
    const int bhw = bid >> 2;
    const int cbase = (bid & 3) * CPC;
    const int t = threadIdx.x;
    float m = -3.0e38f;
    for (int i = t; i < NBLK; i += 256) m = fmaxf(m, ws[BM_OFF + i]);
    #pragma unroll
    for (int d = 1; d < 64; d <<= 1) m = fmaxf(m, __shfl_xor(m, d));
    if ((t & 63) == 0) smax[t >> 6] = m;
    __syncthreads();
    const float M = fmaxf(fmaxf(smax[0], smax[1]), fmaxf(smax[2], smax[3]));
    const int b = bhw / (NH*NW);
    const int rem = bhw % (NH*NW);
    const int y = rem / NW, x = rem % NW;
    const float* lp = ws + LOGNUM_OFF + (size_t)bhw*(NC*NO);
    float* dense = ws + DENSE_OFF;
    const int o = t & 31;
    for (int it = 0; it < CPC/8; ++it) {
        const int c = cbase + it*8 + (t >> 5);
        float s = expf(lp[c*32 + o] - M);
        #pragma unroll
        for (int d = 1; d < 32; d <<= 1) s += __shfl_xor(s, d);
        if (o == 0) {
            const int i = c & 31, kk = c >> 5;
            const int ky = kk / 3, kx = kk % 3;
            atomicAdd(&dense[((b*HR + y+ky)*WR + (x+kx))*NI + i], s);
        }
    }
}

// ---------------- Kernel D: final m_step partial moments -------------------
// grid = NBLK, block = 256. Inline global max; ra staged in LDS; slot tail
// with quad==0 sumR (the r3/r4 bug fix: quads hold identical sumR).
__global__ __launch_bounds__(256) void kD(const float* __restrict__ votes,
        const float* __restrict__ acts, float* __restrict__ ws) {
    __shared__ float s_rd[CPC];
    __shared__ float s_ra[CPC*NO];
    __shared__ float smax[4];
    __shared__ float4 r1[128], r2[128];
    __shared__ float sSR[64];
    const int bid = blockIdx.x;
    const int bhw = bid >> 2;
    const int cbase = (bid & 3) * CPC;
    const int t = threadIdx.x;
    const int b = bhw / (NH*NW);
    const int remhw = bhw % (NH*NW);
    const int y = remhw / NW, x = remhw % NW;
    float m = -3.0e38f;
    for (int i = t; i < NBLK; i += 256) m = fmaxf(m, ws[BM_OFF + i]);
    #pragma unroll
    for (int d = 1; d < 64; d <<= 1) m = fmaxf(m, __shfl_xor(m, d));
    if ((t & 63) == 0) smax[t >> 6] = m;
    if (t < CPC) {
        const int c = cbase + t;
        const int i = c & 31, kk = c >> 5;
        const int ky = kk / 3, kx = kk % 3;
        float dn = ws[DENSE_OFF + ((b*HR + y+ky)*WR + (x+kx))*NI + i];
        s_rd[t] = acts[bhw*NC + c] / (dn + EPSF);
    }
    __syncthreads();
    const float M = fmaxf(fmaxf(smax[0], smax[1]), fmaxf(smax[2], smax[3]));
    const float* lp = ws + LOGNUM_OFF + (size_t)bhw*(NC*NO) + (size_t)cbase*32;
    for (int idx = t; idx < CPC*NO; idx += 256)
        s_ra[idx] = s_rd[idx >> 5] * expf(lp[idx] - M);
    __syncthreads();
    const int child_sub = t >> 7;
    const int rem = t & 127;
    const int o = rem >> 2;
    const int quad = rem & 3;
    const float4* vb4 = (const float4*)votes + (size_t)bhw*(VPB/4);
    float s1[4] = {0,0,0,0}, s2[4] = {0,0,0,0};
    float sumR = 0.f;
    #pragma unroll 6
    for (int it = 0; it < ITERS; ++it) {
        const int c_loc = it*2 + child_sub;
        float4 v = vb4[(size_t)(cbase + c_loc)*128 + rem];
        float ra = s_ra[c_loc*32 + o];          // 4-lane broadcast
        s1[0] += ra*v.x; s2[0] = fmaf(ra*v.x, v.x, s2[0]);
        s1[1] += ra*v.y; s2[1] = fmaf(ra*v.y, v.y, s2[1]);
        s1[2] += ra*v.z; s2[2] = fmaf(ra*v.z, v.z, s2[2]);
        s1[3] += ra*v.w; s2[3] = fmaf(ra*v.w, v.w, s2[3]);
        sumR += ra;
    }
    // per-(child_sub, o) partial: quads are identical, take quad 0's only
    if (quad == 0) sSR[child_sub*32 + o] = sumR;
    if (child_sub) {
        r1[rem] = make_float4(s1[0], s1[1], s1[2], s1[3]);
        r2[rem] = make_float4(s2[0], s2[1], s2[2], s2[3]);
    }
    __syncthreads();
    if (!child_sub) {
        float4 o1 = r1[rem], o2 = r2[rem];
        ((float4*)(ws + PD_S1))[bid*128 + rem] =
            make_float4(s1[0]+o1.x, s1[1]+o1.y, s1[2]+o1.z, s1[3]+o1.w);
        ((float4*)(ws + PD_S2))[bid*128 + rem] =
            make_float4(s2[0]+o2.x, s2[1]+o2.y, s2[2]+o2.z, s2[3]+o2.w);
    }
    if (t < 32) ws[PD_SR + bid*32 + t] = sSR[t] + sSR[32 + t];
}

// ---------------- Kernel D2: reduce chunk slots, write outputs -------------
// grid = NBHW*2, block = 256, t = (o_loc<<4)|a
__global__ __launch_bounds__(256) void kD2(const float* __restrict__ beta_a,
        const float* __restrict__ beta_u, const float* __restrict__ ws,
        float* __restrict__ out) {
    const int bid = blockIdx.x;
    const int bhw = bid >> 1;
    const int obase = (bid & 1) * 16;
    const int t = threadIdx.x;
    const int a = t & 15;
    const int o = obase + (t >> 4);
    float s1 = 0.f, s2 = 0.f, sumR = 0.f;
    #pragma unroll
    for (int ch = 0; ch < CH; ++ch) {
        s1   += ws[PD_S1 + (size_t)(bhw*CH + ch)*512 + obase*16 + t];
        s2   += ws[PD_S2 + (size_t)(bhw*CH + ch)*512 + obase*16 + t];
        sumR += ws[PD_SR + (bhw*CH + ch)*32 + o];
    }
    float mu  = s1 / (sumR + EPSF);
    float sig = (s2 - mu*(2.f*s1 - mu*sumR)) / (sumR + EPSF) + MINVAR;
    out[bhw*512 + obase*16 + t] = mu;            // poses (b,h,w,o,a,a)
    float cost = (beta_u[o] - 0.5f*logf(sig + EPSF)) * sumR;
    #pragma unroll
    for (int d = 1; d < 16; d <<= 1) cost += __shfl_xor(cost, d);
    if (a == 0) {
        float aj = 1.0f/(1.0f + expf(-TEMPF*(beta_a[o] - cost)));
        out[NBHW*512 + bhw*32 + o] = aj;         // acts (b,h,w,o)
    }
}

extern "C" void kernel_launch(void* const* d_in, const int* in_sizes, int n_in,
                              void* d_out, int out_size, void* d_ws, size_t ws_size,
                              hipStream_t stream) {
    const float* votes  = (const float*)d_in[0];
    const float* acts   = (const float*)d_in[1];
    const float* beta_a = (const float*)d_in[2];
    const float* beta_u = (const float*)d_in[3];
    float* ws  = (float*)d_ws;
    float* out = (float*)d_out;

    kA <<<NBLK,   256, 0, stream>>>(votes, acts, ws);
    kB <<<NBLK,   256, 0, stream>>>(votes, beta_a, beta_u, ws);
    kC <<<NBHW*4, 256, 0, stream>>>(ws);
    kD <<<NBLK,   256, 0, stream>>>(votes, acts, ws);
    kD2<<<NBHW*2, 256, 0, stream>>>(beta_a, beta_u, ws, out);
}